// Round 1
// baseline (1318.122 us; speedup 1.0000x reference)
//
#include <hip/hip_runtime.h>
#include <math.h>

#define Bsz 64
#define Lsz 64
#define Dsz 512
#define T1 4.0f
#define T2 5.0f
#define T3 10.0f
#define EPSF 1e-8f

#define PK 36   // GEMM1 k-tile row stride (floats): rows 16b+tx -> banks 4tx, 2-way max
#define PS 65   // raw-score / attn row stride: column walks rotate banks
#define PP 68   // P / EchT row stride: rows 16x+t -> banks 4t, 2-way max; 16B aligned

// ---------------- w1: ||sent[i,q,:]|| for all 4096 rows ----------------
__global__ void w1_kernel(const float* __restrict__ sent, float* __restrict__ w1) {
    int wid  = (blockIdx.x * blockDim.x + threadIdx.x) >> 6;   // 0..4095
    int lane = threadIdx.x & 63;
    const float* row = sent + (size_t)wid * Dsz;
    float s = 0.f;
    for (int k = lane * 4; k < Dsz; k += 256) {
        float4 v = *(const float4*)(row + k);
        s += v.x * v.x + v.y * v.y + v.z * v.z + v.w * v.w;
    }
    #pragma unroll
    for (int off = 32; off; off >>= 1) s += __shfl_down(s, off);
    if (lane == 0) w1[wid] = sqrtf(s);
}

// ---------------- main: one block per (i,j) pair ----------------
__global__ __launch_bounds__(256, 3) void pair_kernel(
        const float* __restrict__ ecg, const float* __restrict__ sent,
        const float* __restrict__ w1, float* __restrict__ simval,
        float* __restrict__ out) {

    __shared__ float bufA[4608];      // phase1: Et[64][36]+St[64][36]; phase2: At[64][65]; phase3: EchT[64][68]
    __shared__ float Ssc[64 * PS];    // raw scores S[s][q] — persists (w12 fold)
    __shared__ float Pm[64 * PP];     // attn2 P[q][s]
    __shared__ float w2arr[64];
    __shared__ float w12arr[64];

    const int tid = threadIdx.x;
    const int i = blockIdx.x >> 6;    // sent index
    const int j = blockIdx.x & 63;    // ecg index
    const float* E  = ecg  + (size_t)j * (Lsz * Dsz);
    const float* Sm = sent + (size_t)i * (Lsz * Dsz);

    const int ty = tid >> 4;          // 0..15 -> s-group
    const int tx = tid & 15;          // 0..15 -> q-group

    // ---------- GEMM1: S[s][q] = E[s,:] . Sm[q,:], K=512 ----------
    float* Et = bufA;
    float* St = bufA + 64 * PK;
    float acc[4][4];
    #pragma unroll
    for (int a = 0; a < 4; a++)
        #pragma unroll
        for (int b = 0; b < 4; b++) acc[a][b] = 0.f;

    const int lr = tid >> 3;          // 0..31
    const int lc = tid & 7;           // 0..7

    for (int k0 = 0; k0 < Dsz; k0 += 32) {
        float4 e0 = *(const float4*)(E  + (size_t)lr * Dsz + k0 + lc * 4);
        float4 e1 = *(const float4*)(E  + (size_t)(lr + 32) * Dsz + k0 + lc * 4);
        float4 s0 = *(const float4*)(Sm + (size_t)lr * Dsz + k0 + lc * 4);
        float4 s1 = *(const float4*)(Sm + (size_t)(lr + 32) * Dsz + k0 + lc * 4);
        __syncthreads();   // previous iter's tile reads done
        *(float4*)(Et + lr * PK + lc * 4)        = e0;
        *(float4*)(Et + (lr + 32) * PK + lc * 4) = e1;
        *(float4*)(St + lr * PK + lc * 4)        = s0;
        *(float4*)(St + (lr + 32) * PK + lc * 4) = s1;
        __syncthreads();
        #pragma unroll
        for (int kk = 0; kk < 8; kk++) {
            float4 ea[4], eb[4];
            #pragma unroll
            for (int a = 0; a < 4; a++) ea[a] = *(const float4*)(Et + (a * 16 + ty) * PK + kk * 4);
            #pragma unroll
            for (int b = 0; b < 4; b++) eb[b] = *(const float4*)(St + (b * 16 + tx) * PK + kk * 4);
            #pragma unroll
            for (int a = 0; a < 4; a++)
                #pragma unroll
                for (int b = 0; b < 4; b++)
                    acc[a][b] += ea[a].x * eb[b].x + ea[a].y * eb[b].y +
                                 ea[a].z * eb[b].z + ea[a].w * eb[b].w;
        }
    }
    __syncthreads();
    #pragma unroll
    for (int a = 0; a < 4; a++)
        #pragma unroll
        for (int b = 0; b < 4; b++)
            Ssc[(a * 16 + ty) * PS + (b * 16 + tx)] = acc[a][b];
    __syncthreads();

    // ---------- softmax over q (rows of Ssc) -> At (aliases bufA) ----------
    float* At = bufA;
    {
        const int s = tid >> 2, c = tid & 3;
        const float* rowp = Ssc + s * PS + c * 16;
        float m = -1e30f;
        float v[16];
        #pragma unroll
        for (int t = 0; t < 16; t++) { v[t] = rowp[t]; m = fmaxf(m, v[t]); }
        m = fmaxf(m, __shfl_xor(m, 1));
        m = fmaxf(m, __shfl_xor(m, 2));
        float sum = 0.f;
        #pragma unroll
        for (int t = 0; t < 16; t++) { v[t] = __expf(v[t] - m); sum += v[t]; }
        sum += __shfl_xor(sum, 1);
        sum += __shfl_xor(sum, 2);
        float inv = 1.f / sum;
        #pragma unroll
        for (int t = 0; t < 16; t++) At[s * PS + c * 16 + t] = v[t] * inv;
    }
    __syncthreads();

    // ---------- softmax over s of T1*attn (columns of At) -> P[q][s] ----------
    {
        const int q = tid >> 2, c = tid & 3;
        float m = -1e30f;
        float v[16];
        #pragma unroll
        for (int t = 0; t < 16; t++) {
            v[t] = T1 * At[(c * 16 + t) * PS + q];
            m = fmaxf(m, v[t]);
        }
        m = fmaxf(m, __shfl_xor(m, 1));
        m = fmaxf(m, __shfl_xor(m, 2));
        float sum = 0.f;
        #pragma unroll
        for (int t = 0; t < 16; t++) { v[t] = __expf(v[t] - m); sum += v[t]; }
        sum += __shfl_xor(sum, 1);
        sum += __shfl_xor(sum, 2);
        float inv = 1.f / sum;
        #pragma unroll
        for (int t = 0; t < 16; t++) Pm[q * PP + c * 16 + t] = v[t] * inv;
    }
    __syncthreads();

    // ---------- att_maps output for diagonal blocks ----------
    if (i == j) {
        float* om = out + 1 + (size_t)i * 4096;
        #pragma unroll
        for (int r = 0; r < 16; r++) {
            int elem = r * 256 + tid;               // q*64+s
            om[elem] = Pm[(elem >> 6) * PP + (elem & 63)];
        }
    }

    // ---------- GEMM2: wctx[q][d] = sum_s P[q][s]*E[s][d]; only ||wctx|| needed ----------
    float* EchT = bufA;                              // [d][s] transposed chunk
    float w2p[4] = {0.f, 0.f, 0.f, 0.f};
    const int ls  = tid >> 2;                        // 0..63 source row s
    const int lc4 = tid & 3;                         // 0..3

    for (int d0 = 0; d0 < Dsz; d0 += 64) {
        float4 ld[4];
        #pragma unroll
        for (int m2 = 0; m2 < 4; m2++)
            ld[m2] = *(const float4*)(E + (size_t)ls * Dsz + d0 + lc4 * 16 + m2 * 4);
        __syncthreads();   // previous chunk reads (or At reads) done
        #pragma unroll
        for (int m2 = 0; m2 < 4; m2++) {
            int d = lc4 * 16 + m2 * 4;
            EchT[(d + 0) * PP + ls] = ld[m2].x;
            EchT[(d + 1) * PP + ls] = ld[m2].y;
            EchT[(d + 2) * PP + ls] = ld[m2].z;
            EchT[(d + 3) * PP + ls] = ld[m2].w;
        }
        __syncthreads();
        float acc2[4][4];
        #pragma unroll
        for (int a = 0; a < 4; a++)
            #pragma unroll
            for (int b = 0; b < 4; b++) acc2[a][b] = 0.f;
        #pragma unroll
        for (int kk = 0; kk < 16; kk++) {
            float4 pa[4], pe[4];
            #pragma unroll
            for (int a = 0; a < 4; a++) pa[a] = *(const float4*)(Pm   + (a * 16 + ty) * PP + kk * 4);
            #pragma unroll
            for (int b = 0; b < 4; b++) pe[b] = *(const float4*)(EchT + (b * 16 + tx) * PP + kk * 4);
            #pragma unroll
            for (int a = 0; a < 4; a++)
                #pragma unroll
                for (int b = 0; b < 4; b++)
                    acc2[a][b] += pa[a].x * pe[b].x + pa[a].y * pe[b].y +
                                  pa[a].z * pe[b].z + pa[a].w * pe[b].w;
        }
        #pragma unroll
        for (int a = 0; a < 4; a++)
            #pragma unroll
            for (int b = 0; b < 4; b++) w2p[a] += acc2[a][b] * acc2[a][b];
    }

    // reduce ||wctx[q]||^2 across the 16 lanes sharing q (tx dimension, contiguous in wave)
    #pragma unroll
    for (int a = 0; a < 4; a++) {
        float v = w2p[a];
        v += __shfl_xor(v, 8);
        v += __shfl_xor(v, 4);
        v += __shfl_xor(v, 2);
        v += __shfl_xor(v, 1);
        if (tx == 0) w2arr[a * 16 + ty] = v;
    }
    __syncthreads();

    // ---------- w12[q] = sum_s P[q][s] * S_raw[s][q]  (algebraic fold) ----------
    {
        const int q = tid >> 2, c = tid & 3;
        float p = 0.f;
        #pragma unroll
        for (int t = 0; t < 16; t++) {
            int s = c * 16 + t;
            p += Pm[q * PP + s] * Ssc[s * PS + q];
        }
        p += __shfl_xor(p, 1);
        p += __shfl_xor(p, 2);
        if (c == 0) w12arr[q] = p;
    }
    __syncthreads();

    // ---------- cos, LSE over q, sim value ----------
    if (tid < 64) {
        float w2  = sqrtf(w2arr[tid]);
        float ww1 = w1[i * 64 + tid];
        float cosv = w12arr[tid] / fmaxf(ww1 * w2, EPSF);
        float e = __expf(T2 * cosv);   // <= e^5, no overflow
        #pragma unroll
        for (int off = 32; off; off >>= 1) e += __shfl_down(e, off);
        if (tid == 0) simval[i * 64 + j] = T3 * __logf(e);
    }
}

// ---------------- loss from the 64x64 sim matrix ----------------
__global__ void loss_kernel(const float* __restrict__ val, float* __restrict__ out) {
    int i = threadIdx.x;   // 64 threads, one wave
    float rmax = -1e30f, cmax = -1e30f;
    for (int jj = 0; jj < 64; jj++) {
        rmax = fmaxf(rmax, val[i * 64 + jj]);
        cmax = fmaxf(cmax, val[jj * 64 + i]);
    }
    float rs = 0.f, cs = 0.f;
    for (int jj = 0; jj < 64; jj++) {
        rs += __expf(val[i * 64 + jj] - rmax);
        cs += __expf(val[jj * 64 + i] - cmax);
    }
    float rlse = rmax + __logf(rs);
    float clse = cmax + __logf(cs);
    // sim = val^T: logp0 diag uses column-lse of val, logp1 diag uses row-lse
    float part = 2.f * val[i * 64 + i] - rlse - clse;
    #pragma unroll
    for (int off = 32; off; off >>= 1) part += __shfl_down(part, off);
    if (i == 0) out[0] = -part / 128.f;
}

extern "C" void kernel_launch(void* const* d_in, const int* in_sizes, int n_in,
                              void* d_out, int out_size, void* d_ws, size_t ws_size,
                              hipStream_t stream) {
    (void)in_sizes; (void)n_in; (void)out_size; (void)ws_size;
    const float* ecg  = (const float*)d_in[0];
    const float* sent = (const float*)d_in[1];
    float* out = (float*)d_out;
    float* w1  = (float*)d_ws;            // 4096 floats
    float* val = (float*)d_ws + 4096;     // 4096 floats (sim pre-transpose)

    w1_kernel  <<<1024, 256, 0, stream>>>(sent, w1);
    pair_kernel<<<4096, 256, 0, stream>>>(ecg, sent, w1, val, out);
    loss_kernel<<<1,    64,  0, stream>>>(val, out);
}

// Round 2
// 219.197 us; speedup vs baseline: 6.0134x; 6.0134x over previous
//
#include <hip/hip_runtime.h>
#include <math.h>

typedef __attribute__((ext_vector_type(8))) short short8;
typedef __attribute__((ext_vector_type(4))) float f32x4;
typedef unsigned int uint;
typedef unsigned short ushort;

#define T1 4.0f
#define T2 5.0f
#define T3 10.0f
#define EPSF 1e-8f

__device__ inline ushort f2bf(float x) {
    union { float f; uint u; } a; a.f = x;
    uint r = a.u + 0x7FFFu + ((a.u >> 16) & 1u);
    return (ushort)(r >> 16);
}
__device__ inline float bf2f(ushort h) {
    union { uint u; float f; } a; a.u = ((uint)h) << 16;
    return a.f;
}

// ---------------- w1: ||sent[i,q,:]|| for all 4096 rows ----------------
__global__ void w1_kernel(const float* __restrict__ sent, float* __restrict__ w1) {
    int wid  = (blockIdx.x * blockDim.x + threadIdx.x) >> 6;
    int lane = threadIdx.x & 63;
    const float* row = sent + (size_t)wid * 512;
    float s = 0.f;
    for (int k = lane * 4; k < 512; k += 256) {
        float4 v = *(const float4*)(row + k);
        s += v.x * v.x + v.y * v.y + v.z * v.z + v.w * v.w;
    }
    #pragma unroll
    for (int off = 32; off; off >>= 1) s += __shfl_down(s, off);
    if (lane == 0) w1[wid] = sqrtf(s);
}

// ---------------- G_j = E_j E_j^T, split to bf16 hi/lo ----------------
__global__ __launch_bounds__(256) void gprep_kernel(const float* __restrict__ ecg,
        ushort* __restrict__ Ghi, ushort* __restrict__ Glo) {
    __shared__ __align__(16) float Et[64 * 36];
    const int j = blockIdx.x;
    const float* E = ecg + (size_t)j * (64 * 512);
    const int tid = threadIdx.x;
    const int ty = tid >> 4, tx = tid & 15;
    const int sr = tid >> 3, sc = tid & 7;
    float acc[4][4];
    #pragma unroll
    for (int a = 0; a < 4; a++)
        #pragma unroll
        for (int b = 0; b < 4; b++) acc[a][b] = 0.f;

    for (int k0 = 0; k0 < 512; k0 += 32) {
        float4 e0 = *(const float4*)(E + (size_t)sr * 512 + k0 + sc * 4);
        float4 e1 = *(const float4*)(E + (size_t)(sr + 32) * 512 + k0 + sc * 4);
        __syncthreads();
        *(float4*)(Et + sr * 36 + sc * 4)        = e0;
        *(float4*)(Et + (sr + 32) * 36 + sc * 4) = e1;
        __syncthreads();
        #pragma unroll
        for (int kk = 0; kk < 8; kk++) {
            float4 ea[4], eb[4];
            #pragma unroll
            for (int a = 0; a < 4; a++) ea[a] = *(const float4*)(Et + (a * 16 + ty) * 36 + kk * 4);
            #pragma unroll
            for (int b = 0; b < 4; b++) eb[b] = *(const float4*)(Et + (b * 16 + tx) * 36 + kk * 4);
            #pragma unroll
            for (int a = 0; a < 4; a++)
                #pragma unroll
                for (int b = 0; b < 4; b++)
                    acc[a][b] += ea[a].x * eb[b].x + ea[a].y * eb[b].y +
                                 ea[a].z * eb[b].z + ea[a].w * eb[b].w;
        }
    }
    #pragma unroll
    for (int a = 0; a < 4; a++)
        #pragma unroll
        for (int b = 0; b < 4; b++) {
            float g = acc[a][b];
            ushort h = f2bf(g);
            ushort l = f2bf(g - bf2f(h));
            size_t idx = (size_t)j * 4096 + (a * 16 + ty) * 64 + (b * 16 + tx);
            Ghi[idx] = h;
            Glo[idx] = l;
        }
}

// ---------------- main: one block per (i,j) pair ----------------
__global__ __launch_bounds__(256, 4) void pair_kernel(
        const float* __restrict__ ecg, const float* __restrict__ sent,
        const float* __restrict__ w1g, const ushort* __restrict__ Ghi,
        const ushort* __restrict__ Glo,
        float* __restrict__ simval, float* __restrict__ out) {

    // regA (20480 B): GEMM1 staging (Ehi/Elo/Shi/Slo, 64x20 words each) -> Ssc[64][65] -> GhiL/GloL
    // regB (18432 B): At[64][65] -> Phi/Plo bf16 (64 rows x 144 B each)
    __shared__ __align__(16) float regA[5120];
    __shared__ __align__(16) float regB[4608];
    __shared__ float w2half[128];
    __shared__ float w12arr[64];

    const int tid = threadIdx.x;

    // XCD-aware swizzle: 8x8 (i,j) tiles, one tile at a time per XCD
    const int bn   = blockIdx.x;
    const int xcd  = bn & 7;
    const int slot = bn >> 3;
    const int tile = xcd * 8 + (slot >> 6);   // 0..63
    const int wp   = slot & 63;
    const int i = (tile >> 3) * 8 + (wp >> 3);
    const int j = (tile & 7) * 8 + (wp & 7);

    const float* E  = ecg  + (size_t)j * (64 * 512);
    const float* Sm = sent + (size_t)i * (64 * 512);

    const int lane = tid & 63, wv = tid >> 6;
    const int wq = wv >> 1, wn = wv & 1;       // 2x2 wave quadrant (m-half, n-half)
    const int quad = lane >> 4, ln = lane & 15;

    uint* sA = (uint*)regA;
    // staging bases (words, stride 20/row): Ehi 0, Elo 1280, Shi 2560, Slo 3840
    const int sr = tid >> 3, sc = tid & 7;

    // ---------- GEMM1: S[s][q] = E[s,:] . Sm[q,:], bf16 split MFMA ----------
    f32x4 acc[2][2];
    #pragma unroll
    for (int a = 0; a < 2; a++)
        #pragma unroll
        for (int b = 0; b < 2; b++) acc[a][b] = (f32x4){0.f, 0.f, 0.f, 0.f};

    for (int k0 = 0; k0 < 512; k0 += 32) {
        float4 ev[2], sv[2];
        ev[0] = *(const float4*)(E  + (size_t)sr * 512 + k0 + sc * 4);
        ev[1] = *(const float4*)(E  + (size_t)(sr + 32) * 512 + k0 + sc * 4);
        sv[0] = *(const float4*)(Sm + (size_t)sr * 512 + k0 + sc * 4);
        sv[1] = *(const float4*)(Sm + (size_t)(sr + 32) * 512 + k0 + sc * 4);
        __syncthreads();   // prev chunk's frag reads done
        #pragma unroll
        for (int h = 0; h < 2; h++) {
            int row = sr + 32 * h;
            float4 v = ev[h];
            ushort h0 = f2bf(v.x), h1 = f2bf(v.y), h2 = f2bf(v.z), h3 = f2bf(v.w);
            uint2 hh; hh.x = (uint)h0 | ((uint)h1 << 16); hh.y = (uint)h2 | ((uint)h3 << 16);
            ushort l0 = f2bf(v.x - bf2f(h0)), l1 = f2bf(v.y - bf2f(h1));
            ushort l2 = f2bf(v.z - bf2f(h2)), l3 = f2bf(v.w - bf2f(h3));
            uint2 ll; ll.x = (uint)l0 | ((uint)l1 << 16); ll.y = (uint)l2 | ((uint)l3 << 16);
            *(uint2*)(sA +        row * 20 + sc * 2) = hh;
            *(uint2*)(sA + 1280 + row * 20 + sc * 2) = ll;
            v = sv[h];
            h0 = f2bf(v.x); h1 = f2bf(v.y); h2 = f2bf(v.z); h3 = f2bf(v.w);
            hh.x = (uint)h0 | ((uint)h1 << 16); hh.y = (uint)h2 | ((uint)h3 << 16);
            l0 = f2bf(v.x - bf2f(h0)); l1 = f2bf(v.y - bf2f(h1));
            l2 = f2bf(v.z - bf2f(h2)); l3 = f2bf(v.w - bf2f(h3));
            ll.x = (uint)l0 | ((uint)l1 << 16); ll.y = (uint)l2 | ((uint)l3 << 16);
            *(uint2*)(sA + 2560 + row * 20 + sc * 2) = hh;
            *(uint2*)(sA + 3840 + row * 20 + sc * 2) = ll;
        }
        __syncthreads();
        short8 ah[2], al[2], bh[2], bl[2];
        #pragma unroll
        for (int mi = 0; mi < 2; mi++) {
            int r = 32 * wq + 16 * mi + ln;
            ah[mi] = *(const short8*)(sA +        r * 20 + quad * 4);
            al[mi] = *(const short8*)(sA + 1280 + r * 20 + quad * 4);
        }
        #pragma unroll
        for (int ni = 0; ni < 2; ni++) {
            int r = 32 * wn + 16 * ni + ln;
            bh[ni] = *(const short8*)(sA + 2560 + r * 20 + quad * 4);
            bl[ni] = *(const short8*)(sA + 3840 + r * 20 + quad * 4);
        }
        #pragma unroll
        for (int mi = 0; mi < 2; mi++)
            #pragma unroll
            for (int ni = 0; ni < 2; ni++) {
                acc[mi][ni] = __builtin_amdgcn_mfma_f32_16x16x32_bf16(ah[mi], bh[ni], acc[mi][ni], 0, 0, 0);
                acc[mi][ni] = __builtin_amdgcn_mfma_f32_16x16x32_bf16(ah[mi], bl[ni], acc[mi][ni], 0, 0, 0);
                acc[mi][ni] = __builtin_amdgcn_mfma_f32_16x16x32_bf16(al[mi], bh[ni], acc[mi][ni], 0, 0, 0);
            }
    }
    __syncthreads();   // all frag reads done before Ssc overwrites staging

    // C-write: S[s][q] into regA (stride 65)
    float* Ssc = regA;
    #pragma unroll
    for (int mi = 0; mi < 2; mi++)
        #pragma unroll
        for (int ni = 0; ni < 2; ni++)
            #pragma unroll
            for (int r = 0; r < 4; r++) {
                int s = 32 * wq + 16 * mi + quad * 4 + r;
                int q = 32 * wn + 16 * ni + ln;
                Ssc[s * 65 + q] = acc[mi][ni][r];
            }
    __syncthreads();

    // ---------- softmax over q (rows of Ssc) -> At in regB ----------
    float* At = regB;
    {
        const int s = tid >> 2, c = tid & 3;
        float v[16];
        float m = -1e30f;
        #pragma unroll
        for (int t = 0; t < 16; t++) { v[t] = Ssc[s * 65 + c * 16 + t]; m = fmaxf(m, v[t]); }
        m = fmaxf(m, __shfl_xor(m, 1));
        m = fmaxf(m, __shfl_xor(m, 2));
        float sum = 0.f;
        #pragma unroll
        for (int t = 0; t < 16; t++) { v[t] = __expf(v[t] - m); sum += v[t]; }
        sum += __shfl_xor(sum, 1);
        sum += __shfl_xor(sum, 2);
        float inv = 1.f / sum;
        #pragma unroll
        for (int t = 0; t < 16; t++) At[s * 65 + c * 16 + t] = v[t] * inv;
    }
    __syncthreads();

    // ---------- softmax over s of T1*At (columns) -> P; w12 fold; att_maps ----------
    char* PhiB = (char*)regB;
    char* PloB = PhiB + 9216;
    {
        const int q = tid >> 2, c = tid & 3;
        float v[16];
        float m = -1e30f;
        #pragma unroll
        for (int t = 0; t < 16; t++) {
            v[t] = T1 * At[(c * 16 + t) * 65 + q];
            m = fmaxf(m, v[t]);
        }
        m = fmaxf(m, __shfl_xor(m, 1));
        m = fmaxf(m, __shfl_xor(m, 2));
        float sum = 0.f;
        #pragma unroll
        for (int t = 0; t < 16; t++) { v[t] = __expf(v[t] - m); sum += v[t]; }
        sum += __shfl_xor(sum, 1);
        sum += __shfl_xor(sum, 2);
        float inv = 1.f / sum;
        #pragma unroll
        for (int t = 0; t < 16; t++) v[t] *= inv;

        // w12[q] = sum_s P[q][s] * S_raw[s][q]  (P still in regs, Ssc in regA)
        float p12 = 0.f;
        #pragma unroll
        for (int t = 0; t < 16; t++) p12 += v[t] * Ssc[(c * 16 + t) * 65 + q];
        p12 += __shfl_xor(p12, 1);
        p12 += __shfl_xor(p12, 2);
        if (c == 0) w12arr[q] = p12;

        if (i == j) {
            float* om = out + 1 + (size_t)i * 4096;
            #pragma unroll
            for (int t = 0; t < 16; t++) om[q * 64 + c * 16 + t] = v[t];
        }
        __syncthreads();   // all At reads done before Phi/Plo overwrite regB

        ushort hi[16], lo[16];
        #pragma unroll
        for (int t = 0; t < 16; t++) {
            hi[t] = f2bf(v[t]);
            lo[t] = f2bf(v[t] - bf2f(hi[t]));
        }
        uint4 H;
        H.x = (uint)hi[0] | ((uint)hi[1] << 16);  H.y = (uint)hi[2] | ((uint)hi[3] << 16);
        H.z = (uint)hi[4] | ((uint)hi[5] << 16);  H.w = (uint)hi[6] | ((uint)hi[7] << 16);
        *(uint4*)(PhiB + q * 144 + c * 32) = H;
        H.x = (uint)hi[8] | ((uint)hi[9] << 16);  H.y = (uint)hi[10] | ((uint)hi[11] << 16);
        H.z = (uint)hi[12] | ((uint)hi[13] << 16); H.w = (uint)hi[14] | ((uint)hi[15] << 16);
        *(uint4*)(PhiB + q * 144 + c * 32 + 16) = H;
        H.x = (uint)lo[0] | ((uint)lo[1] << 16);  H.y = (uint)lo[2] | ((uint)lo[3] << 16);
        H.z = (uint)lo[4] | ((uint)lo[5] << 16);  H.w = (uint)lo[6] | ((uint)lo[7] << 16);
        *(uint4*)(PloB + q * 144 + c * 32) = H;
        H.x = (uint)lo[8] | ((uint)lo[9] << 16);  H.y = (uint)lo[10] | ((uint)lo[11] << 16);
        H.z = (uint)lo[12] | ((uint)lo[13] << 16); H.w = (uint)lo[14] | ((uint)lo[15] << 16);
        *(uint4*)(PloB + q * 144 + c * 32 + 16) = H;
    }
    __syncthreads();   // Ssc dead; Phi/Plo visible

    // ---------- stage G_j (bf16 hi/lo) into regA ----------
    {
        char* GhiL = (char*)regA;
        char* GloL = GhiL + 9216;
        const char* srcH = (const char*)(Ghi + (size_t)j * 4096);
        const char* srcL = (const char*)(Glo + (size_t)j * 4096);
        int rr = tid >> 2, cb = tid & 3;
        uint4 g0 = *(const uint4*)(srcH + tid * 32);
        uint4 g1 = *(const uint4*)(srcH + tid * 32 + 16);
        uint4 g2 = *(const uint4*)(srcL + tid * 32);
        uint4 g3 = *(const uint4*)(srcL + tid * 32 + 16);
        *(uint4*)(GhiL + rr * 144 + cb * 32)      = g0;
        *(uint4*)(GhiL + rr * 144 + cb * 32 + 16) = g1;
        *(uint4*)(GloL + rr * 144 + cb * 32)      = g2;
        *(uint4*)(GloL + rr * 144 + cb * 32 + 16) = g3;
    }
    __syncthreads();

    // ---------- w2^2[q] = P[q,:] G P[q,:]^T via split MFMA (y = P G, then y.P) ----------
    {
        const char* GhiL = (const char*)regA;
        const char* GloL = GhiL + 9216;
        f32x4 acc2[2][2];
        #pragma unroll
        for (int a = 0; a < 2; a++)
            #pragma unroll
            for (int b = 0; b < 2; b++) acc2[a][b] = (f32x4){0.f, 0.f, 0.f, 0.f};
        #pragma unroll
        for (int ch = 0; ch < 2; ch++) {
            short8 pah[2], pal[2], gbh[2], gbl[2];
            #pragma unroll
            for (int mi = 0; mi < 2; mi++) {
                int q = 32 * wq + 16 * mi + ln;
                pah[mi] = *(const short8*)(PhiB + q * 144 + ch * 64 + quad * 16);
                pal[mi] = *(const short8*)(PloB + q * 144 + ch * 64 + quad * 16);
            }
            #pragma unroll
            for (int ni = 0; ni < 2; ni++) {
                int t = 32 * wn + 16 * ni + ln;
                gbh[ni] = *(const short8*)(GhiL + t * 144 + ch * 64 + quad * 16);
                gbl[ni] = *(const short8*)(GloL + t * 144 + ch * 64 + quad * 16);
            }
            #pragma unroll
            for (int mi = 0; mi < 2; mi++)
                #pragma unroll
                for (int ni = 0; ni < 2; ni++) {
                    acc2[mi][ni] = __builtin_amdgcn_mfma_f32_16x16x32_bf16(pah[mi], gbh[ni], acc2[mi][ni], 0, 0, 0);
                    acc2[mi][ni] = __builtin_amdgcn_mfma_f32_16x16x32_bf16(pah[mi], gbl[ni], acc2[mi][ni], 0, 0, 0);
                    acc2[mi][ni] = __builtin_amdgcn_mfma_f32_16x16x32_bf16(pal[mi], gbh[ni], acc2[mi][ni], 0, 0, 0);
                }
        }
        // w2^2 partial: sum_t y[q][t] * P[q][t]
        #pragma unroll
        for (int mi = 0; mi < 2; mi++)
            #pragma unroll
            for (int r = 0; r < 4; r++) {
                int q = 32 * wq + 16 * mi + quad * 4 + r;
                float s = 0.f;
                #pragma unroll
                for (int ni = 0; ni < 2; ni++) {
                    int t = 32 * wn + 16 * ni + ln;
                    float Pqt = bf2f(*(const ushort*)(PhiB + q * 144 + t * 2)) +
                                bf2f(*(const ushort*)(PloB + q * 144 + t * 2));
                    s += acc2[mi][ni][r] * Pqt;
                }
                s += __shfl_xor(s, 1);
                s += __shfl_xor(s, 2);
                s += __shfl_xor(s, 4);
                s += __shfl_xor(s, 8);
                if (ln == 0) w2half[wn * 64 + q] = s;
            }
    }
    __syncthreads();

    // ---------- cos, LSE over q, sim ----------
    if (tid < 64) {
        float w2 = sqrtf(fmaxf(w2half[tid] + w2half[64 + tid], 0.f));
        float ww1 = w1g[i * 64 + tid];
        float cosv = w12arr[tid] / fmaxf(ww1 * w2, EPSF);
        float e = __expf(T2 * cosv);
        #pragma unroll
        for (int off = 32; off; off >>= 1) e += __shfl_down(e, off);
        if (tid == 0) simval[i * 64 + j] = T3 * __logf(e);
    }
}

// ---------------- loss from the 64x64 sim matrix ----------------
__global__ void loss_kernel(const float* __restrict__ val, float* __restrict__ out) {
    int i = threadIdx.x;
    float rmax = -1e30f, cmax = -1e30f;
    for (int jj = 0; jj < 64; jj++) {
        rmax = fmaxf(rmax, val[i * 64 + jj]);
        cmax = fmaxf(cmax, val[jj * 64 + i]);
    }
    float rs = 0.f, cs = 0.f;
    for (int jj = 0; jj < 64; jj++) {
        rs += __expf(val[i * 64 + jj] - rmax);
        cs += __expf(val[jj * 64 + i] - cmax);
    }
    float rlse = rmax + __logf(rs);
    float clse = cmax + __logf(cs);
    float part = 2.f * val[i * 64 + i] - rlse - clse;
    #pragma unroll
    for (int off = 32; off; off >>= 1) part += __shfl_down(part, off);
    if (i == 0) out[0] = -part / 128.f;
}

extern "C" void kernel_launch(void* const* d_in, const int* in_sizes, int n_in,
                              void* d_out, int out_size, void* d_ws, size_t ws_size,
                              hipStream_t stream) {
    (void)in_sizes; (void)n_in; (void)out_size; (void)ws_size;
    const float* ecg  = (const float*)d_in[0];
    const float* sent = (const float*)d_in[1];
    float* out = (float*)d_out;
    float* w1  = (float*)d_ws;                                  // 4096 f
    float* val = w1 + 4096;                                     // 4096 f
    ushort* Ghi = (ushort*)((char*)d_ws + 32768);               // 64*4096 bf16
    ushort* Glo = Ghi + 64 * 4096;                              // 64*4096 bf16

    w1_kernel   <<<1024, 256, 0, stream>>>(sent, w1);
    gprep_kernel<<<64,   256, 0, stream>>>(ecg, Ghi, Glo);
    pair_kernel <<<4096, 256, 0, stream>>>(ecg, sent, w1, Ghi, Glo, val, out);
    loss_kernel <<<1,    64,  0, stream>>>(val, out);
}

// Round 3
// 168.992 us; speedup vs baseline: 7.7999x; 1.2971x over previous
//
#include <hip/hip_runtime.h>
#include <math.h>

typedef __attribute__((ext_vector_type(8))) short short8;
typedef __attribute__((ext_vector_type(4))) float f32x4;
typedef unsigned int uint;
typedef unsigned short ushort;

#define T1 4.0f
#define T2 5.0f
#define T3 10.0f
#define EPSF 1e-8f

__device__ inline ushort f2bf(float x) {
    union { float f; uint u; } a; a.f = x;
    uint r = a.u + 0x7FFFu + ((a.u >> 16) & 1u);
    return (ushort)(r >> 16);
}
__device__ inline float bf2f(ushort h) {
    union { uint u; float f; } a; a.u = ((uint)h) << 16;
    return a.f;
}

// async global->LDS, 16B per lane; LDS dest is wave-uniform base + lane*16
#define GLDS(gsrc, ldst) \
    __builtin_amdgcn_global_load_lds( \
        (const __attribute__((address_space(1))) uint*)(gsrc), \
        (__attribute__((address_space(3))) uint*)(ldst), 16, 0, 0)

// ---------------- prep: fp32 -> bf16 hi/lo in LDS-image layout (+ w1 norms) ----------------
// Layout per tensor-row-block idx: [kc 0..15][row r 0..63][4 chunks of 16B, chunk c at
// physical slot (c + (r>>1)) & 3]  => 65536 B per idx.
__global__ __launch_bounds__(256) void prep_kernel(
        const float* __restrict__ ecg, const float* __restrict__ sent,
        char* __restrict__ EH, char* __restrict__ EL,
        char* __restrict__ SH, char* __restrict__ SL, float* __restrict__ w1) {
    __shared__ float partial[256];
    const int bid = blockIdx.x;
    const int tensor = bid >> 6, idx = bid & 63;
    const float* src = (tensor ? sent : ecg) + (size_t)idx * 32768;
    char* dh = (tensor ? SH : EH) + (size_t)idx * 65536;
    char* dl = (tensor ? SL : EL) + (size_t)idx * 65536;
    const int tid = threadIdx.x;
    const int r = tid & 63;
    float s2 = 0.f;
    #pragma unroll
    for (int it = 0; it < 4; it++) {
        int kc = it * 4 + (tid >> 6);
        const float* p = src + r * 512 + kc * 32;
        char* oh = dh + kc * 4096 + r * 64;
        char* ol = dl + kc * 4096 + r * 64;
        #pragma unroll
        for (int c = 0; c < 4; c++) {
            float4 v0 = *(const float4*)(p + c * 8);
            float4 v1 = *(const float4*)(p + c * 8 + 4);
            float x[8] = {v0.x, v0.y, v0.z, v0.w, v1.x, v1.y, v1.z, v1.w};
            uint hw[4], lw[4];
            #pragma unroll
            for (int e = 0; e < 4; e++) {
                float a0 = x[2 * e], a1 = x[2 * e + 1];
                ushort h0 = f2bf(a0), h1 = f2bf(a1);
                hw[e] = (uint)h0 | ((uint)h1 << 16);
                ushort l0 = f2bf(a0 - bf2f(h0)), l1 = f2bf(a1 - bf2f(h1));
                lw[e] = (uint)l0 | ((uint)l1 << 16);
                s2 += a0 * a0 + a1 * a1;
            }
            int phys = (c + (r >> 1)) & 3;
            uint4 H; H.x = hw[0]; H.y = hw[1]; H.z = hw[2]; H.w = hw[3];
            *(uint4*)(oh + phys * 16) = H;
            uint4 L; L.x = lw[0]; L.y = lw[1]; L.z = lw[2]; L.w = lw[3];
            *(uint4*)(ol + phys * 16) = L;
        }
    }
    partial[tid] = s2;
    __syncthreads();
    if (tensor == 1 && tid < 64) {
        float t = partial[tid] + partial[tid + 64] + partial[tid + 128] + partial[tid + 192];
        w1[idx * 64 + tid] = sqrtf(t);
    }
}

// ---------------- G_j = E_j E_j^T, bf16 hi/lo, rows 128B with chunk rotation (p+t)&7 ----------
__global__ __launch_bounds__(256) void gprep_kernel(const float* __restrict__ ecg,
        char* __restrict__ Gp) {
    __shared__ __align__(16) float Et[64 * 36];
    const int j = blockIdx.x;
    const float* E = ecg + (size_t)j * (64 * 512);
    const int tid = threadIdx.x;
    const int ty = tid >> 4, tx = tid & 15;
    const int sr = tid >> 3, sc = tid & 7;
    float acc[4][4];
    #pragma unroll
    for (int a = 0; a < 4; a++)
        #pragma unroll
        for (int b = 0; b < 4; b++) acc[a][b] = 0.f;

    for (int k0 = 0; k0 < 512; k0 += 32) {
        float4 e0 = *(const float4*)(E + (size_t)sr * 512 + k0 + sc * 4);
        float4 e1 = *(const float4*)(E + (size_t)(sr + 32) * 512 + k0 + sc * 4);
        __syncthreads();
        *(float4*)(Et + sr * 36 + sc * 4)        = e0;
        *(float4*)(Et + (sr + 32) * 36 + sc * 4) = e1;
        __syncthreads();
        #pragma unroll
        for (int kk = 0; kk < 8; kk++) {
            float4 ea[4], eb[4];
            #pragma unroll
            for (int a = 0; a < 4; a++) ea[a] = *(const float4*)(Et + (a * 16 + ty) * 36 + kk * 4);
            #pragma unroll
            for (int b = 0; b < 4; b++) eb[b] = *(const float4*)(Et + (b * 16 + tx) * 36 + kk * 4);
            #pragma unroll
            for (int a = 0; a < 4; a++)
                #pragma unroll
                for (int b = 0; b < 4; b++)
                    acc[a][b] += ea[a].x * eb[b].x + ea[a].y * eb[b].y +
                                 ea[a].z * eb[b].z + ea[a].w * eb[b].w;
        }
    }
    #pragma unroll
    for (int a = 0; a < 4; a++)
        #pragma unroll
        for (int b = 0; b < 4; b++) {
            float g = acc[a][b];
            ushort h = f2bf(g);
            ushort l = f2bf(g - bf2f(h));
            int t = a * 16 + ty, u = b * 16 + tx;
            int phys = ((u >> 3) + t) & 7;
            char* base = Gp + (size_t)j * 16384 + t * 128 + phys * 16 + (u & 7) * 2;
            *(ushort*)base = h;
            *(ushort*)(base + 8192) = l;
        }
}

// ---------------- main: one block per 2x2 pairs (128x128 GEMM1 tile) ----------------
__global__ __launch_bounds__(256, 4) void pair_kernel(
        const char* __restrict__ EH, const char* __restrict__ EL,
        const char* __restrict__ SH, const char* __restrict__ SL,
        const char* __restrict__ Gp, const float* __restrict__ w1g,
        float* __restrict__ simval, float* __restrict__ out) {

    // lds: GEMM staging [EH 8K|EL 8K|SH 8K|SL 8K]=32K; later Ssc(64x65 f32, 16640)/G(16K)/y(64x68 f32, 17408)
    // at offset 0, P (Phi 8K + Plo 8K) at 17408; total 33792
    __shared__ __align__(16) char lds[33792];
    __shared__ float mz[64], w12a[64], w2sq[64];

    const int tid = threadIdx.x;
    // XCD-aware mapping: XCD x owns bi-band [4x,4x+3], sweeps 4x4 big-tiles
    const int bn = blockIdx.x;
    const int xcd = bn & 7, slot = bn >> 3;
    const int T = xcd * 8 + (slot >> 4);
    const int wp = slot & 15;
    const int bi = (T >> 3) * 4 + (wp >> 2);
    const int bj = (T & 7) * 4 + (wp & 3);
    const int i0 = bi * 2, j0 = bj * 2;

    const int wv = tid >> 6, lane = tid & 63;
    const int wq = wv >> 1, wn = wv & 1;
    const int quad = lane >> 4, ln = lane & 15;

    // ---- GEMM1: S[128 rows=(a,s)][128 cols=(b,q)], K=512, 3-term bf16 split ----
    // scatter mapping: wave tile rows 64*(mi>>1)+32*wq+16*(mi&1), cols 64*(ni>>1)+32*wn+16*(ni&1)
    int aoff[4], boff[4];
    #pragma unroll
    for (int mi = 0; mi < 4; mi++) {
        int R = 64 * (mi >> 1) + 32 * wq + 16 * (mi & 1) + ln;
        aoff[mi] = R * 64 + ((quad + (R >> 1)) & 3) * 16;
    }
    #pragma unroll
    for (int ni = 0; ni < 4; ni++) {
        int R = 64 * (ni >> 1) + 32 * wn + 16 * (ni & 1) + ln;
        boff[ni] = 16384 + R * 64 + ((quad + (R >> 1)) & 3) * 16;
    }

    const char* gA; const char* gB; int ldoff;
    if (wv == 0)      { gA = EH + (size_t)j0 * 65536;       gB = EH + (size_t)(j0 + 1) * 65536; ldoff = 0; }
    else if (wv == 1) { gA = EL + (size_t)j0 * 65536;       gB = EL + (size_t)(j0 + 1) * 65536; ldoff = 8192; }
    else if (wv == 2) { gA = SH + (size_t)i0 * 65536;       gB = SH + (size_t)(i0 + 1) * 65536; ldoff = 16384; }
    else              { gA = SL + (size_t)i0 * 65536;       gB = SL + (size_t)(i0 + 1) * 65536; ldoff = 24576; }
    gA += lane * 16; gB += lane * 16;

    f32x4 acc[4][4];
    #pragma unroll
    for (int a = 0; a < 4; a++)
        #pragma unroll
        for (int b = 0; b < 4; b++) acc[a][b] = (f32x4){0.f, 0.f, 0.f, 0.f};

    for (int kc = 0; kc < 16; kc++) {
        #pragma unroll
        for (int n = 0; n < 4; n++) GLDS(gA + n * 1024, lds + ldoff + n * 1024);
        #pragma unroll
        for (int n = 0; n < 4; n++) GLDS(gB + n * 1024, lds + ldoff + 4096 + n * 1024);
        gA += 4096; gB += 4096;
        __syncthreads();   // drains vmcnt: staging complete
        short8 bh[4], bl[4];
        #pragma unroll
        for (int ni = 0; ni < 4; ni++) {
            bh[ni] = *(const short8*)(lds + boff[ni]);
            bl[ni] = *(const short8*)(lds + boff[ni] + 8192);
        }
        #pragma unroll
        for (int mi = 0; mi < 4; mi++) {
            short8 ah = *(const short8*)(lds + aoff[mi]);
            short8 al = *(const short8*)(lds + aoff[mi] + 8192);
            #pragma unroll
            for (int ni = 0; ni < 4; ni++) {
                acc[mi][ni] = __builtin_amdgcn_mfma_f32_16x16x32_bf16(ah, bh[ni], acc[mi][ni], 0, 0, 0);
                acc[mi][ni] = __builtin_amdgcn_mfma_f32_16x16x32_bf16(ah, bl[ni], acc[mi][ni], 0, 0, 0);
                acc[mi][ni] = __builtin_amdgcn_mfma_f32_16x16x32_bf16(al, bh[ni], acc[mi][ni], 0, 0, 0);
            }
        }
        __syncthreads();   // frag reads done before next chunk overwrite
    }

    float* Ssc = (float*)lds;
    float* yb  = (float*)lds;
    char*  Pb  = lds + 17408;

    // ---- per-pair phases ----
    #pragma unroll
    for (int pr = 0; pr < 4; pr++) {
        const int a = pr >> 1, b = pr & 1;
        const int i = i0 + b, j = j0 + a;

        // C-write this pair's quadrant into Ssc[s][q] (stride 65)
        #pragma unroll
        for (int dm = 0; dm < 2; dm++)
            #pragma unroll
            for (int dn = 0; dn < 2; dn++) {
                int s = 32 * wq + 16 * dm + quad * 4;
                int q = 32 * wn + 16 * dn + ln;
                f32x4 v = acc[2 * a + dm][2 * b + dn];
                Ssc[(s + 0) * 65 + q] = v[0];
                Ssc[(s + 1) * 65 + q] = v[1];
                Ssc[(s + 2) * 65 + q] = v[2];
                Ssc[(s + 3) * 65 + q] = v[3];
            }
        __syncthreads();

        // softmax1 stats over q (rows): mz[s] = m + ln(Z)
        {
            const int s = tid >> 2, c = tid & 3;
            float vv[16]; float m = -1e30f;
            #pragma unroll
            for (int t = 0; t < 16; t++) { vv[t] = Ssc[s * 65 + c * 16 + t]; m = fmaxf(m, vv[t]); }
            m = fmaxf(m, __shfl_xor(m, 1));
            m = fmaxf(m, __shfl_xor(m, 2));
            float sum = 0.f;
            #pragma unroll
            for (int t = 0; t < 16; t++) sum += __expf(vv[t] - m);
            sum += __shfl_xor(sum, 1);
            sum += __shfl_xor(sum, 2);
            if (c == 0) mz[s] = m + __logf(sum);
        }
        __syncthreads();

        // softmax2 over s (columns): P[q][s]; fold w12; att_maps; pack P hi/lo into Pb
        {
            const int q = tid >> 2, c = tid & 3;
            float at[16];
            #pragma unroll
            for (int t = 0; t < 16; t++)
                at[t] = __expf(Ssc[(c * 16 + t) * 65 + q] - mz[c * 16 + t]);
            float m2 = -1e30f;
            #pragma unroll
            for (int t = 0; t < 16; t++) m2 = fmaxf(m2, T1 * at[t]);
            m2 = fmaxf(m2, __shfl_xor(m2, 1));
            m2 = fmaxf(m2, __shfl_xor(m2, 2));
            float sum = 0.f;
            #pragma unroll
            for (int t = 0; t < 16; t++) { at[t] = __expf(T1 * at[t] - m2); sum += at[t]; }
            sum += __shfl_xor(sum, 1);
            sum += __shfl_xor(sum, 2);
            float inv = 1.f / sum;
            #pragma unroll
            for (int t = 0; t < 16; t++) at[t] *= inv;   // at[] now = P[q][16c+t]

            float p12 = 0.f;
            #pragma unroll
            for (int t = 0; t < 16; t++) p12 += at[t] * Ssc[(c * 16 + t) * 65 + q];
            p12 += __shfl_xor(p12, 1);
            p12 += __shfl_xor(p12, 2);
            if (c == 0) w12a[q] = p12;

            if (i == j) {
                float* om = out + 1 + (size_t)i * 4096;
                #pragma unroll
                for (int t = 0; t < 16; t++) om[q * 64 + c * 16 + t] = at[t];
            }

            uint hw[8], lw[8];
            #pragma unroll
            for (int e = 0; e < 8; e++) {
                ushort h0 = f2bf(at[2 * e]), h1 = f2bf(at[2 * e + 1]);
                hw[e] = (uint)h0 | ((uint)h1 << 16);
                ushort l0 = f2bf(at[2 * e] - bf2f(h0)), l1 = f2bf(at[2 * e + 1] - bf2f(h1));
                lw[e] = (uint)l0 | ((uint)l1 << 16);
            }
            int p0 = (2 * c + q) & 7, p1 = (2 * c + 1 + q) & 7;
            uint4 W;
            W.x = hw[0]; W.y = hw[1]; W.z = hw[2]; W.w = hw[3];
            *(uint4*)(Pb + q * 128 + p0 * 16) = W;
            W.x = hw[4]; W.y = hw[5]; W.z = hw[6]; W.w = hw[7];
            *(uint4*)(Pb + q * 128 + p1 * 16) = W;
            W.x = lw[0]; W.y = lw[1]; W.z = lw[2]; W.w = lw[3];
            *(uint4*)(Pb + 8192 + q * 128 + p0 * 16) = W;
            W.x = lw[4]; W.y = lw[5]; W.z = lw[6]; W.w = lw[7];
            *(uint4*)(Pb + 8192 + q * 128 + p1 * 16) = W;
        }
        __syncthreads();   // Ssc dead; P visible

        // stage G_j (pre-swizzled, straight 16KB copy into Ssc region)
        {
            const char* gs = Gp + (size_t)j * 16384 + tid * 64;
            char* gd = lds + tid * 64;
            uint4 g0 = *(const uint4*)(gs);
            uint4 g1 = *(const uint4*)(gs + 16);
            uint4 g2 = *(const uint4*)(gs + 32);
            uint4 g3 = *(const uint4*)(gs + 48);
            *(uint4*)(gd)      = g0;
            *(uint4*)(gd + 16) = g1;
            *(uint4*)(gd + 32) = g2;
            *(uint4*)(gd + 48) = g3;
        }
        __syncthreads();

        // quadratic: y = P * G (3-term), 64x64
        f32x4 acc2[2][2];
        #pragma unroll
        for (int x = 0; x < 2; x++)
            #pragma unroll
            for (int y = 0; y < 2; y++) acc2[x][y] = (f32x4){0.f, 0.f, 0.f, 0.f};
        #pragma unroll
        for (int ch = 0; ch < 2; ch++) {
            short8 pah[2], pal[2], gbh[2], gbl[2];
            #pragma unroll
            for (int m2i = 0; m2i < 2; m2i++) {
                int q = 32 * wq + 16 * m2i + ln;
                int ph = ((ch * 4 + quad) + q) & 7;
                pah[m2i] = *(const short8*)(Pb + q * 128 + ph * 16);
                pal[m2i] = *(const short8*)(Pb + 8192 + q * 128 + ph * 16);
            }
            #pragma unroll
            for (int n2i = 0; n2i < 2; n2i++) {
                int u = 32 * wn + 16 * n2i + ln;
                int ph = ((ch * 4 + quad) + u) & 7;
                gbh[n2i] = *(const short8*)(lds + u * 128 + ph * 16);
                gbl[n2i] = *(const short8*)(lds + 8192 + u * 128 + ph * 16);
            }
            #pragma unroll
            for (int m2i = 0; m2i < 2; m2i++)
                #pragma unroll
                for (int n2i = 0; n2i < 2; n2i++) {
                    acc2[m2i][n2i] = __builtin_amdgcn_mfma_f32_16x16x32_bf16(pah[m2i], gbh[n2i], acc2[m2i][n2i], 0, 0, 0);
                    acc2[m2i][n2i] = __builtin_amdgcn_mfma_f32_16x16x32_bf16(pah[m2i], gbl[n2i], acc2[m2i][n2i], 0, 0, 0);
                    acc2[m2i][n2i] = __builtin_amdgcn_mfma_f32_16x16x32_bf16(pal[m2i], gbh[n2i], acc2[m2i][n2i], 0, 0, 0);
                }
        }
        __syncthreads();   // G reads done

        // y write (stride 68, 16B-aligned rows)
        #pragma unroll
        for (int m2i = 0; m2i < 2; m2i++)
            #pragma unroll
            for (int n2i = 0; n2i < 2; n2i++) {
                int q = 32 * wq + 16 * m2i + quad * 4;
                int u = 32 * wn + 16 * n2i + ln;
                f32x4 v = acc2[m2i][n2i];
                yb[(q + 0) * 68 + u] = v[0];
                yb[(q + 1) * 68 + u] = v[1];
                yb[(q + 2) * 68 + u] = v[2];
                yb[(q + 3) * 68 + u] = v[3];
            }
        __syncthreads();

        // fold: w2sq[q] = sum_t y[q][t] * P[q][t]
        {
            const int q = tid >> 2, c = tid & 3;
            const float* yr = yb + q * 68 + 16 * c;
            float4 y0 = *(const float4*)(yr);
            float4 y1 = *(const float4*)(yr + 4);
            float4 y2 = *(const float4*)(yr + 8);
            float4 y3 = *(const float4*)(yr + 12);
            float yv[16] = {y0.x,y0.y,y0.z,y0.w, y1.x,y1.y,y1.z,y1.w,
                            y2.x,y2.y,y2.z,y2.w, y3.x,y3.y,y3.z,y3.w};
            int p0 = (2 * c + q) & 7, p1 = (2 * c + 1 + q) & 7;
            uint4 H0 = *(const uint4*)(Pb + q * 128 + p0 * 16);
            uint4 H1 = *(const uint4*)(Pb + q * 128 + p1 * 16);
            uint4 L0 = *(const uint4*)(Pb + 8192 + q * 128 + p0 * 16);
            uint4 L1 = *(const uint4*)(Pb + 8192 + q * 128 + p1 * 16);
            uint hw[8] = {H0.x,H0.y,H0.z,H0.w, H1.x,H1.y,H1.z,H1.w};
            uint lw[8] = {L0.x,L0.y,L0.z,L0.w, L1.x,L1.y,L1.z,L1.w};
            float s = 0.f;
            #pragma unroll
            for (int e = 0; e < 8; e++) {
                float q0 = bf2f((ushort)(hw[e] & 0xFFFFu)) + bf2f((ushort)(lw[e] & 0xFFFFu));
                float q1 = bf2f((ushort)(hw[e] >> 16))     + bf2f((ushort)(lw[e] >> 16));
                s += q0 * yv[2 * e] + q1 * yv[2 * e + 1];
            }
            s += __shfl_xor(s, 1);
            s += __shfl_xor(s, 2);
            if (c == 0) w2sq[q] = s;
        }
        __syncthreads();

        // cos, LSE over q, sim
        if (tid < 64) {
            float w2 = sqrtf(fmaxf(w2sq[tid], 0.f));
            float cosv = w12a[tid] / fmaxf(w1g[i * 64 + tid] * w2, EPSF);
            float e = __expf(T2 * cosv);
            #pragma unroll
            for (int off = 32; off; off >>= 1) e += __shfl_down(e, off);
            if (tid == 0) simval[i * 64 + j] = T3 * __logf(e);
        }
        __syncthreads();
    }
}

// ---------------- loss from the 64x64 sim matrix ----------------
__global__ void loss_kernel(const float* __restrict__ val, float* __restrict__ out) {
    int i = threadIdx.x;
    float rmax = -1e30f, cmax = -1e30f;
    for (int jj = 0; jj < 64; jj++) {
        rmax = fmaxf(rmax, val[i * 64 + jj]);
        cmax = fmaxf(cmax, val[jj * 64 + i]);
    }
    float rs = 0.f, cs = 0.f;
    for (int jj = 0; jj < 64; jj++) {
        rs += __expf(val[i * 64 + jj] - rmax);
        cs += __expf(val[jj * 64 + i] - cmax);
    }
    float rlse = rmax + __logf(rs);
    float clse = cmax + __logf(cs);
    float part = 2.f * val[i * 64 + i] - rlse - clse;
    #pragma unroll
    for (int off = 32; off; off >>= 1) part += __shfl_down(part, off);
    if (i == 0) out[0] = -part / 128.f;
}

extern "C" void kernel_launch(void* const* d_in, const int* in_sizes, int n_in,
                              void* d_out, int out_size, void* d_ws, size_t ws_size,
                              hipStream_t stream) {
    (void)in_sizes; (void)n_in; (void)out_size; (void)ws_size;
    const float* ecg  = (const float*)d_in[0];
    const float* sent = (const float*)d_in[1];
    float* out = (float*)d_out;

    char* ws = (char*)d_ws;
    float* w1v  = (float*)ws;                     // 16 KB
    float* simv = (float*)(ws + 16384);           // 16 KB
    char* EH = ws + 32768;                        // 4 MB each
    char* EL = EH + (size_t)64 * 65536;
    char* SH = EL + (size_t)64 * 65536;
    char* SL = SH + (size_t)64 * 65536;
    char* Gp = SL + (size_t)64 * 65536;           // 1 MB

    prep_kernel <<<128, 256, 0, stream>>>(ecg, sent, EH, EL, SH, SL, w1v);
    gprep_kernel<<<64,  256, 0, stream>>>(ecg, Gp);
    pair_kernel <<<1024, 256, 0, stream>>>(EH, EL, SH, SL, Gp, w1v, simv, out);
    loss_kernel <<<1,   64,  0, stream>>>(simv, out);
}

// Round 4
// 151.341 us; speedup vs baseline: 8.7096x; 1.1166x over previous
//
#include <hip/hip_runtime.h>
#include <math.h>

typedef __attribute__((ext_vector_type(8))) short short8;
typedef __attribute__((ext_vector_type(4))) float f32x4;
typedef unsigned int uint;
typedef unsigned short ushort;

#define T1 4.0f
#define T2 5.0f
#define T3 10.0f
#define EPSF 1e-8f
#define SST 68   // S^T / yT row stride (floats): rows 16B-aligned

__device__ inline ushort f2bf(float x) {
    union { float f; uint u; } a; a.f = x;
    uint r = a.u + 0x7FFFu + ((a.u >> 16) & 1u);
    return (ushort)(r >> 16);
}
__device__ inline float bf2f(ushort h) {
    union { uint u; float f; } a; a.u = ((uint)h) << 16;
    return a.f;
}

// async global->LDS, 16B per lane; LDS dest is wave-uniform base + lane*16
#define GLDS(gsrc, ldst) \
    __builtin_amdgcn_global_load_lds( \
        (const __attribute__((address_space(1))) uint*)(gsrc), \
        (__attribute__((address_space(3))) uint*)(ldst), 16, 0, 0)

// ---------------- prep: fp32 -> bf16 hi/lo in LDS-image layout (+ w1 norms) ----------------
// Layout per row-block idx: [kc 0..15][row r 0..63][4 chunks of 16B, logical chunk c at
// physical slot (c + (r>>1)) & 3]  => 65536 B per idx.
__global__ __launch_bounds__(256) void prep_kernel(
        const float* __restrict__ ecg, const float* __restrict__ sent,
        char* __restrict__ EH, char* __restrict__ EL,
        char* __restrict__ SH, char* __restrict__ SL, float* __restrict__ w1) {
    __shared__ float partial[256];
    const int bid = blockIdx.x;
    const int tensor = bid >> 6, idx = bid & 63;
    const float* src = (tensor ? sent : ecg) + (size_t)idx * 32768;
    char* dh = (tensor ? SH : EH) + (size_t)idx * 65536;
    char* dl = (tensor ? SL : EL) + (size_t)idx * 65536;
    const int tid = threadIdx.x;
    const int r = tid & 63;
    float s2 = 0.f;
    #pragma unroll
    for (int it = 0; it < 4; it++) {
        int kc = it * 4 + (tid >> 6);
        const float* p = src + r * 512 + kc * 32;
        char* oh = dh + kc * 4096 + r * 64;
        char* ol = dl + kc * 4096 + r * 64;
        #pragma unroll
        for (int c = 0; c < 4; c++) {
            float4 v0 = *(const float4*)(p + c * 8);
            float4 v1 = *(const float4*)(p + c * 8 + 4);
            float x[8] = {v0.x, v0.y, v0.z, v0.w, v1.x, v1.y, v1.z, v1.w};
            uint hw[4], lw[4];
            #pragma unroll
            for (int e = 0; e < 4; e++) {
                float a0 = x[2 * e], a1 = x[2 * e + 1];
                ushort h0 = f2bf(a0), h1 = f2bf(a1);
                hw[e] = (uint)h0 | ((uint)h1 << 16);
                ushort l0 = f2bf(a0 - bf2f(h0)), l1 = f2bf(a1 - bf2f(h1));
                lw[e] = (uint)l0 | ((uint)l1 << 16);
                s2 += a0 * a0 + a1 * a1;
            }
            int phys = (c + (r >> 1)) & 3;
            uint4 H; H.x = hw[0]; H.y = hw[1]; H.z = hw[2]; H.w = hw[3];
            *(uint4*)(oh + phys * 16) = H;
            uint4 L; L.x = lw[0]; L.y = lw[1]; L.z = lw[2]; L.w = lw[3];
            *(uint4*)(ol + phys * 16) = L;
        }
    }
    partial[tid] = s2;
    __syncthreads();
    if (tensor == 1 && tid < 64) {
        float t = partial[tid] + partial[tid + 64] + partial[tid + 128] + partial[tid + 192];
        w1[idx * 64 + tid] = sqrtf(t);
    }
}

// ---------------- G_j = E_j E_j^T via 3-term bf16 MFMA from prepped planes ----------------
// Output layout: row t (128B), element u at phys chunk ((u>>3)+t)&7; lo plane +8192.
__global__ __launch_bounds__(256) void gprep_kernel(
        const char* __restrict__ EH, const char* __restrict__ EL, char* __restrict__ Gp) {
    __shared__ __align__(16) char lds[8192];
    const int j = blockIdx.x;
    const int tid = threadIdx.x;
    const int wv = tid >> 6, lane = tid & 63;
    const int wq = wv >> 1, wn = wv & 1;
    const int quad = lane >> 4, ln = lane & 15;
    const char* srcH = EH + (size_t)j * 65536 + wv * 1024 + lane * 16;
    const char* srcL = EL + (size_t)j * 65536 + wv * 1024 + lane * 16;

    int ao[2], bo[2];
    #pragma unroll
    for (int mi = 0; mi < 2; mi++) {
        int R = 32 * wq + 16 * mi + ln;
        ao[mi] = R * 64 + ((quad + (R >> 1)) & 3) * 16;
    }
    #pragma unroll
    for (int ni = 0; ni < 2; ni++) {
        int R = 32 * wn + 16 * ni + ln;
        bo[ni] = R * 64 + ((quad + (R >> 1)) & 3) * 16;
    }

    f32x4 acc[2][2];
    #pragma unroll
    for (int a = 0; a < 2; a++)
        #pragma unroll
        for (int b = 0; b < 2; b++) acc[a][b] = (f32x4){0.f, 0.f, 0.f, 0.f};

    for (int kc = 0; kc < 16; kc++) {
        GLDS(srcH + (size_t)kc * 4096, lds + wv * 1024);
        GLDS(srcL + (size_t)kc * 4096, lds + 4096 + wv * 1024);
        __syncthreads();
        short8 ah[2], al[2], bh[2], bl[2];
        #pragma unroll
        for (int mi = 0; mi < 2; mi++) {
            ah[mi] = *(const short8*)(lds + ao[mi]);
            al[mi] = *(const short8*)(lds + 4096 + ao[mi]);
        }
        #pragma unroll
        for (int ni = 0; ni < 2; ni++) {
            bh[ni] = *(const short8*)(lds + bo[ni]);
            bl[ni] = *(const short8*)(lds + 4096 + bo[ni]);
        }
        #pragma unroll
        for (int mi = 0; mi < 2; mi++)
            #pragma unroll
            for (int ni = 0; ni < 2; ni++) {
                acc[mi][ni] = __builtin_amdgcn_mfma_f32_16x16x32_bf16(ah[mi], bh[ni], acc[mi][ni], 0, 0, 0);
                acc[mi][ni] = __builtin_amdgcn_mfma_f32_16x16x32_bf16(ah[mi], bl[ni], acc[mi][ni], 0, 0, 0);
                acc[mi][ni] = __builtin_amdgcn_mfma_f32_16x16x32_bf16(al[mi], bh[ni], acc[mi][ni], 0, 0, 0);
            }
        __syncthreads();
    }
    #pragma unroll
    for (int mi = 0; mi < 2; mi++)
        #pragma unroll
        for (int ni = 0; ni < 2; ni++)
            #pragma unroll
            for (int r = 0; r < 4; r++) {
                int t = 32 * wq + 16 * mi + quad * 4 + r;
                int u = 32 * wn + 16 * ni + ln;
                float g = acc[mi][ni][r];
                ushort h = f2bf(g);
                ushort l = f2bf(g - bf2f(h));
                char* base = Gp + (size_t)j * 16384 + t * 128 + (((u >> 3) + t) & 7) * 16 + (u & 7) * 2;
                *(ushort*)base = h;
                *(ushort*)(base + 8192) = l;
            }
}

// ---------------- main: one block per 2x2 pairs (128x128 GEMM1 tile) ----------------
__global__ __launch_bounds__(256, 4) void pair_kernel(
        const char* __restrict__ EH, const char* __restrict__ EL,
        const char* __restrict__ SH, const char* __restrict__ SL,
        const char* __restrict__ Gp, const float* __restrict__ w1g,
        float* __restrict__ simval, float* __restrict__ out) {

    // lds: GEMM staging [EH 8K|EL 8K|SH 8K|SL 8K]=32K; then region0 = SsT(64x68 f32)/G(16K)/yT,
    // P (Phi 8K + Plo 8K) at 17408..33792
    __shared__ __align__(16) char lds[33792];
    __shared__ __align__(16) float mz[64];
    __shared__ float w12all[256], w2all[256];

    const int tid = threadIdx.x;
    // XCD-aware mapping
    const int bn = blockIdx.x;
    const int xcd = bn & 7, slot = bn >> 3;
    const int T = xcd * 8 + (slot >> 4);
    const int wp = slot & 15;
    const int bi = (T >> 3) * 4 + (wp >> 2);
    const int bj = (T & 7) * 4 + (wp & 3);
    const int i0 = bi * 2, j0 = bj * 2;

    const int wv = tid >> 6, lane = tid & 63;
    const int wq = wv >> 1, wn = wv & 1;
    const int quad = lane >> 4, ln = lane & 15;

    int aoff[4], boff[4];
    #pragma unroll
    for (int mi = 0; mi < 4; mi++) {
        int R = 64 * (mi >> 1) + 32 * wq + 16 * (mi & 1) + ln;
        aoff[mi] = R * 64 + ((quad + (R >> 1)) & 3) * 16;
    }
    #pragma unroll
    for (int ni = 0; ni < 4; ni++) {
        int R = 64 * (ni >> 1) + 32 * wn + 16 * (ni & 1) + ln;
        boff[ni] = 16384 + R * 64 + ((quad + (R >> 1)) & 3) * 16;
    }

    const char* gA; const char* gB; int ldoff;
    if (wv == 0)      { gA = EH + (size_t)j0 * 65536;       gB = EH + (size_t)(j0 + 1) * 65536; ldoff = 0; }
    else if (wv == 1) { gA = EL + (size_t)j0 * 65536;       gB = EL + (size_t)(j0 + 1) * 65536; ldoff = 8192; }
    else if (wv == 2) { gA = SH + (size_t)i0 * 65536;       gB = SH + (size_t)(i0 + 1) * 65536; ldoff = 16384; }
    else              { gA = SL + (size_t)i0 * 65536;       gB = SL + (size_t)(i0 + 1) * 65536; ldoff = 24576; }
    gA += lane * 16; gB += lane * 16;

    f32x4 acc[4][4];
    #pragma unroll
    for (int a = 0; a < 4; a++)
        #pragma unroll
        for (int b = 0; b < 4; b++) acc[a][b] = (f32x4){0.f, 0.f, 0.f, 0.f};

    for (int kc = 0; kc < 16; kc++) {
        #pragma unroll
        for (int n = 0; n < 4; n++) GLDS(gA + n * 1024, lds + ldoff + n * 1024);
        #pragma unroll
        for (int n = 0; n < 4; n++) GLDS(gB + n * 1024, lds + ldoff + 4096 + n * 1024);
        gA += 4096; gB += 4096;
        __syncthreads();
        short8 bh[4], bl[4];
        #pragma unroll
        for (int ni = 0; ni < 4; ni++) {
            bh[ni] = *(const short8*)(lds + boff[ni]);
            bl[ni] = *(const short8*)(lds + boff[ni] + 8192);
        }
        #pragma unroll
        for (int mi = 0; mi < 4; mi++) {
            short8 ah = *(const short8*)(lds + aoff[mi]);
            short8 al = *(const short8*)(lds + aoff[mi] + 8192);
            #pragma unroll
            for (int ni = 0; ni < 4; ni++) {
                acc[mi][ni] = __builtin_amdgcn_mfma_f32_16x16x32_bf16(ah, bh[ni], acc[mi][ni], 0, 0, 0);
                acc[mi][ni] = __builtin_amdgcn_mfma_f32_16x16x32_bf16(ah, bl[ni], acc[mi][ni], 0, 0, 0);
                acc[mi][ni] = __builtin_amdgcn_mfma_f32_16x16x32_bf16(al, bh[ni], acc[mi][ni], 0, 0, 0);
            }
        }
        __syncthreads();
    }

    float* SsT = (float*)lds;          // [q][s], stride SST
    float* yT  = (float*)lds;          // [t][q], stride SST (aliases)
    char*  Pb  = lds + 17408;          // Phi 8K + Plo 8K

    #pragma unroll
    for (int pr = 0; pr < 4; pr++) {
        const int a = pr >> 1, b = pr & 1;
        const int i = i0 + b, j = j0 + a;

        // C-write: SsT[q][s0..s0+3] b128 (f32x4 holds 4 consecutive rows s at col q)
        #pragma unroll
        for (int dm = 0; dm < 2; dm++)
            #pragma unroll
            for (int dn = 0; dn < 2; dn++) {
                int s0 = 32 * wq + 16 * dm + quad * 4;
                int q  = 32 * wn + 16 * dn + ln;
                *(f32x4*)(SsT + q * SST + s0) = acc[2 * a + dm][2 * b + dn];
            }
        __syncthreads();

        // softmax1 stats over q for each row s: mz[s] = m + ln(Z)
        {
            const int s = tid >> 2, c = tid & 3;
            float vv[16]; float m = -1e30f;
            #pragma unroll
            for (int t = 0; t < 16; t++) { vv[t] = SsT[(16 * c + t) * SST + s]; m = fmaxf(m, vv[t]); }
            m = fmaxf(m, __shfl_xor(m, 1));
            m = fmaxf(m, __shfl_xor(m, 2));
            float sum = 0.f;
            #pragma unroll
            for (int t = 0; t < 16; t++) sum += __expf(vv[t] - m);
            sum += __shfl_xor(sum, 1);
            sum += __shfl_xor(sum, 2);
            if (c == 0) mz[s] = m + __logf(sum);
        }
        __syncthreads();

        // softmax2 over s (rows of SsT): P[q][s]; w12 fold in-reg; att_maps; pack P hi/lo
        {
            const int q = tid >> 2, c = tid & 3;
            float sc[16], at[16];
            #pragma unroll
            for (int r4 = 0; r4 < 4; r4++)
                *(f32x4*)(sc + 4 * r4) = *(const f32x4*)(SsT + q * SST + 16 * c + 4 * r4);
            float mzv[16];
            #pragma unroll
            for (int r4 = 0; r4 < 4; r4++)
                *(f32x4*)(mzv + 4 * r4) = *(const f32x4*)(mz + 16 * c + 4 * r4);
            float m2 = -1e30f;
            #pragma unroll
            for (int t = 0; t < 16; t++) {
                at[t] = __expf(sc[t] - mzv[t]);     // attn1
                m2 = fmaxf(m2, T1 * at[t]);
            }
            m2 = fmaxf(m2, __shfl_xor(m2, 1));
            m2 = fmaxf(m2, __shfl_xor(m2, 2));
            float sum = 0.f;
            #pragma unroll
            for (int t = 0; t < 16; t++) { at[t] = __expf(T1 * at[t] - m2); sum += at[t]; }
            sum += __shfl_xor(sum, 1);
            sum += __shfl_xor(sum, 2);
            float inv = 1.f / sum;
            float p12 = 0.f;
            #pragma unroll
            for (int t = 0; t < 16; t++) { at[t] *= inv; p12 += at[t] * sc[t]; }
            p12 += __shfl_xor(p12, 1);
            p12 += __shfl_xor(p12, 2);
            if (c == 0) w12all[pr * 64 + q] = p12;

            if (i == j) {
                float* om = out + 1 + (size_t)i * 4096;
                #pragma unroll
                for (int t = 0; t < 16; t++) om[q * 64 + c * 16 + t] = at[t];
            }

            uint hw[8], lw[8];
            #pragma unroll
            for (int e = 0; e < 8; e++) {
                ushort h0 = f2bf(at[2 * e]), h1 = f2bf(at[2 * e + 1]);
                hw[e] = (uint)h0 | ((uint)h1 << 16);
                ushort l0 = f2bf(at[2 * e] - bf2f(h0)), l1 = f2bf(at[2 * e + 1] - bf2f(h1));
                lw[e] = (uint)l0 | ((uint)l1 << 16);
            }
            int p0 = (2 * c + q) & 7, p1 = (2 * c + 1 + q) & 7;
            uint4 W;
            W.x = hw[0]; W.y = hw[1]; W.z = hw[2]; W.w = hw[3];
            *(uint4*)(Pb + q * 128 + p0 * 16) = W;
            W.x = hw[4]; W.y = hw[5]; W.z = hw[6]; W.w = hw[7];
            *(uint4*)(Pb + q * 128 + p1 * 16) = W;
            W.x = lw[0]; W.y = lw[1]; W.z = lw[2]; W.w = lw[3];
            *(uint4*)(Pb + 8192 + q * 128 + p0 * 16) = W;
            W.x = lw[4]; W.y = lw[5]; W.z = lw[6]; W.w = lw[7];
            *(uint4*)(Pb + 8192 + q * 128 + p1 * 16) = W;
        }
        __syncthreads();   // S dead; P visible

        // stage G_j (pre-swizzled 16KB copy into region 0)
        {
            const char* gs = Gp + (size_t)j * 16384 + tid * 64;
            char* gd = lds + tid * 64;
            uint4 g0 = *(const uint4*)(gs);
            uint4 g1 = *(const uint4*)(gs + 16);
            uint4 g2 = *(const uint4*)(gs + 32);
            uint4 g3 = *(const uint4*)(gs + 48);
            *(uint4*)(gd)      = g0;
            *(uint4*)(gd + 16) = g1;
            *(uint4*)(gd + 32) = g2;
            *(uint4*)(gd + 48) = g3;
        }
        __syncthreads();

        // quadratic: y = P * G (3-term)
        f32x4 acc2[2][2];
        #pragma unroll
        for (int x = 0; x < 2; x++)
            #pragma unroll
            for (int y = 0; y < 2; y++) acc2[x][y] = (f32x4){0.f, 0.f, 0.f, 0.f};
        #pragma unroll
        for (int ch = 0; ch < 2; ch++) {
            short8 pah[2], pal[2], gbh[2], gbl[2];
            #pragma unroll
            for (int m2i = 0; m2i < 2; m2i++) {
                int q = 32 * wq + 16 * m2i + ln;
                int ph = ((ch * 4 + quad) + q) & 7;
                pah[m2i] = *(const short8*)(Pb + q * 128 + ph * 16);
                pal[m2i] = *(const short8*)(Pb + 8192 + q * 128 + ph * 16);
            }
            #pragma unroll
            for (int n2i = 0; n2i < 2; n2i++) {
                int u = 32 * wn + 16 * n2i + ln;
                int ph = ((ch * 4 + quad) + u) & 7;
                gbh[n2i] = *(const short8*)(lds + u * 128 + ph * 16);
                gbl[n2i] = *(const short8*)(lds + 8192 + u * 128 + ph * 16);
            }
            #pragma unroll
            for (int m2i = 0; m2i < 2; m2i++)
                #pragma unroll
                for (int n2i = 0; n2i < 2; n2i++) {
                    acc2[m2i][n2i] = __builtin_amdgcn_mfma_f32_16x16x32_bf16(pah[m2i], gbh[n2i], acc2[m2i][n2i], 0, 0, 0);
                    acc2[m2i][n2i] = __builtin_amdgcn_mfma_f32_16x16x32_bf16(pah[m2i], gbl[n2i], acc2[m2i][n2i], 0, 0, 0);
                    acc2[m2i][n2i] = __builtin_amdgcn_mfma_f32_16x16x32_bf16(pal[m2i], gbh[n2i], acc2[m2i][n2i], 0, 0, 0);
                }
        }
        __syncthreads();   // G reads done

        // yT[t][q0..q0+3] b128 (f32x4 holds 4 consecutive q at col t)
        #pragma unroll
        for (int m2i = 0; m2i < 2; m2i++)
            #pragma unroll
            for (int n2i = 0; n2i < 2; n2i++) {
                int q0 = 32 * wq + 16 * m2i + quad * 4;
                int t  = 32 * wn + 16 * n2i + ln;
                *(f32x4*)(yT + t * SST + q0) = acc2[m2i][n2i];
            }
        __syncthreads();

        // fold: w2all[q] = sum_t y[q][t] * P[q][t]
        {
            const int q = tid >> 2, c = tid & 3;
            int p0 = (2 * c + q) & 7, p1 = (2 * c + 1 + q) & 7;
            uint4 H0 = *(const uint4*)(Pb + q * 128 + p0 * 16);
            uint4 H1 = *(const uint4*)(Pb + q * 128 + p1 * 16);
            uint4 L0 = *(const uint4*)(Pb + 8192 + q * 128 + p0 * 16);
            uint4 L1 = *(const uint4*)(Pb + 8192 + q * 128 + p1 * 16);
            uint hw[8] = {H0.x,H0.y,H0.z,H0.w, H1.x,H1.y,H1.z,H1.w};
            uint lw[8] = {L0.x,L0.y,L0.z,L0.w, L1.x,L1.y,L1.z,L1.w};
            float s = 0.f;
            #pragma unroll
            for (int e = 0; e < 8; e++) {
                float q0v = bf2f((ushort)(hw[e] & 0xFFFFu)) + bf2f((ushort)(lw[e] & 0xFFFFu));
                float q1v = bf2f((ushort)(hw[e] >> 16))     + bf2f((ushort)(lw[e] >> 16));
                s += q0v * yT[(16 * c + 2 * e) * SST + q];
                s += q1v * yT[(16 * c + 2 * e + 1) * SST + q];
            }
            s += __shfl_xor(s, 1);
            s += __shfl_xor(s, 2);
            if (c == 0) w2all[pr * 64 + q] = s;
        }
        __syncthreads();   // yT reads done; next pair may overwrite region 0 and Pb
    }

    // sim tail: wave wv handles pair wv in parallel
    {
        const int pr = wv;
        const int ii = i0 + (pr & 1), jj = j0 + (pr >> 1);
        float w2 = sqrtf(fmaxf(w2all[pr * 64 + lane], 0.f));
        float cosv = w12all[pr * 64 + lane] / fmaxf(w1g[ii * 64 + lane] * w2, EPSF);
        float e = __expf(T2 * cosv);
        #pragma unroll
        for (int off = 32; off; off >>= 1) e += __shfl_down(e, off);
        if (lane == 0) simval[ii * 64 + jj] = T3 * __logf(e);
    }
}

// ---------------- loss from the 64x64 sim matrix ----------------
__global__ __launch_bounds__(256) void loss_kernel(const float* __restrict__ val,
                                                   float* __restrict__ out) {
    __shared__ float v[4096];
    const int tid = threadIdx.x;
    #pragma unroll
    for (int k = 0; k < 4; k++)
        ((float4*)v)[tid + k * 256] = ((const float4*)val)[tid + k * 256];
    __syncthreads();
    if (tid < 64) {
        int i = tid;
        float rmax = -1e30f, cmax = -1e30f;
        for (int jj = 0; jj < 64; jj++) {
            rmax = fmaxf(rmax, v[i * 64 + jj]);
            cmax = fmaxf(cmax, v[jj * 64 + i]);
        }
        float rs = 0.f, cs = 0.f;
        for (int jj = 0; jj < 64; jj++) {
            rs += __expf(v[i * 64 + jj] - rmax);
            cs += __expf(v[jj * 64 + i] - cmax);
        }
        float rlse = rmax + __logf(rs);
        float clse = cmax + __logf(cs);
        float part = 2.f * v[i * 64 + i] - rlse - clse;
        #pragma unroll
        for (int off = 32; off; off >>= 1) part += __shfl_down(part, off);
        if (i == 0) out[0] = -part / 128.f;
    }
}

extern "C" void kernel_launch(void* const* d_in, const int* in_sizes, int n_in,
                              void* d_out, int out_size, void* d_ws, size_t ws_size,
                              hipStream_t stream) {
    (void)in_sizes; (void)n_in; (void)out_size; (void)ws_size;
    const float* ecg  = (const float*)d_in[0];
    const float* sent = (const float*)d_in[1];
    float* out = (float*)d_out;

    char* ws = (char*)d_ws;
    float* w1v  = (float*)ws;                     // 16 KB
    float* simv = (float*)(ws + 16384);           // 16 KB
    char* EH = ws + 32768;                        // 4 MB each
    char* EL = EH + (size_t)64 * 65536;
    char* SH = EL + (size_t)64 * 65536;
    char* SL = SH + (size_t)64 * 65536;
    char* Gp = SL + (size_t)64 * 65536;           // 1 MB

    prep_kernel <<<128, 256, 0, stream>>>(ecg, sent, EH, EL, SH, SL, w1v);
    gprep_kernel<<<64,  256, 0, stream>>>(EH, EL, Gp);
    pair_kernel <<<1024, 256, 0, stream>>>(EH, EL, SH, SL, Gp, w1v, simv, out);
    loss_kernel <<<1,   256, 0, stream>>>(simv, out);
}